// Round 2
// baseline (4684.498 us; speedup 1.0000x reference)
//
#include <hip/hip_runtime.h>
#include <hip/hip_bf16.h>

typedef __hip_bfloat16 bf16;

#define D_H   224
#define D_W   224
#define D_HW  50176      // 224*224
#define NTOK  49         // 7*7 tokens per window
#define SCALE 0.17677669529663687f  // 32^-0.5

__device__ __forceinline__ float b2f(bf16 v) { return __bfloat162float(v); }
__device__ __forceinline__ bf16  f2b(float v) { return __float2bfloat16(v); }

// ---------------------------------------------------------------------------
// K1: one block per window (8192 blocks).
//   LN1 -> shifted-window gather -> QKV GEMM -> 3-head attention
//   (rel-pos bias + shift mask computed analytically) -> proj -> residual.
// Global buffers are FP32; LDS staging is bf16 (threshold is bf16-grade).
// Writes y = x + attn_out to d_out in [B,C,H,W] layout.
// ---------------------------------------------------------------------------
__global__ __launch_bounds__(256) void k_attn(
    const float* __restrict__ x, const float* __restrict__ n1g, const float* __restrict__ n1b,
    const float* __restrict__ qkvw, const float* __restrict__ qkvb, const float* __restrict__ relt,
    const float* __restrict__ projw, const float* __restrict__ projb, float* __restrict__ y)
{
    __shared__ bf16 xnb[NTOK][98];        // tokens (bf16), later reused as attn-out
    __shared__ bf16 qkvs[NTOK][290];      // qkv per token (288 + pad)
    __shared__ __align__(16) char ubuf[96*96*2];  // union: weight tile | score matrix
    bf16* ws = (bf16*)ubuf;               // 96x96 bf16 weight tile
    float (*S)[NTOK] = (float (*)[NTOK])ubuf;     // 49x49 fp32 scores (9.6KB < 18.4KB)
    __shared__ float mean_s[NTOK], rstd_s[NTOK];
    __shared__ int   cnt_s[NTOK];

    const int tid = threadIdx.x;
    const int wi = blockIdx.x;
    const int b  = wi >> 10;        // / 1024 windows per image
    const int nw = wi & 1023;
    const int wh = nw >> 5, ww = nw & 31;

    // ---- gather raw tokens (shifted-window mapping) ----
    for (int idx = tid; idx < NTOK*96; idx += 256) {
        int c = idx / NTOK;
        int n = idx - c*NTOK;
        int r = n / 7, cc = n - r*7;
        int h = wh*7 + r + 3; if (h >= D_H) h -= D_H;   // roll(-3) inverse
        int w = ww*7 + cc + 3; if (w >= D_W) w -= D_W;
        xnb[n][c] = f2b(x[((b*96 + c)*D_H + h)*D_W + w]);
    }
    if (tid < NTOK) {
        // shift-mask region label (on the shifted/partitioned grid)
        int r = tid/7, cc = tid - r*7;
        int sh = wh*7 + r, sw = ww*7 + cc;
        int rh = (sh < 217) ? 0 : ((sh < 221) ? 1 : 2);
        int rw = (sw < 217) ? 0 : ((sw < 221) ? 1 : 2);
        cnt_s[tid] = rh*3 + rw;
    }
    __syncthreads();

    // ---- LayerNorm1 over channels ----
    if (tid < NTOK) {
        float s = 0.f, s2 = 0.f;
        for (int c = 0; c < 96; c++) { float v = b2f(xnb[tid][c]); s += v; s2 += v*v; }
        float m = s * (1.0f/96.0f);
        float var = s2 * (1.0f/96.0f) - m*m;
        mean_s[tid] = m;
        rstd_s[tid] = rsqrtf(var + 1e-5f);
    }
    __syncthreads();
    for (int idx = tid; idx < NTOK*96; idx += 256) {
        int n = idx / 96, c = idx - n*96;
        float v = (b2f(xnb[n][c]) - mean_s[n]) * rstd_s[n] * n1g[c] + n1b[c];
        xnb[n][c] = f2b(v);
    }

    // ---- QKV GEMM: 49x96 @ 96x288, weights staged in LDS (3 chunks of 96 rows) ----
    for (int jc = 0; jc < 3; jc++) {
        __syncthreads();
        for (int idx = tid; idx < 96*96; idx += 256) ws[idx] = f2b(qkvw[jc*9216 + idx]);
        __syncthreads();
        for (int idx = tid; idx < 96*NTOK; idx += 256) {
            int jj = idx / NTOK, n = idx - jj*NTOK;
            int j = jc*96 + jj;
            float acc = qkvb[j];
            for (int c = 0; c < 96; c++) acc += b2f(xnb[n][c]) * b2f(ws[jj*96 + c]);
            qkvs[n][j] = f2b(acc);
        }
    }
    __syncthreads();

    // ---- attention, head by head; output into xnb (reused as ao) ----
    for (int h = 0; h < 3; h++) {
        for (int idx = tid; idx < NTOK*NTOK; idx += 256) {
            int n = idx / NTOK, m = idx - n*NTOK;
            float acc = 0.f;
            for (int d = 0; d < 32; d++)
                acc += b2f(qkvs[n][h*32 + d]) * b2f(qkvs[m][96 + h*32 + d]);
            int r1 = n/7, c1 = n - r1*7, r2 = m/7, c2 = m - r2*7;
            int ridx = (r1 - r2 + 6)*13 + (c1 - c2 + 6);
            acc = acc * SCALE + relt[ridx*3 + h];
            if (cnt_s[n] != cnt_s[m]) acc -= 100.f;
            S[n][m] = acc;
        }
        __syncthreads();
        if (tid < NTOK) {   // row softmax
            float mx = -1e30f;
            for (int m = 0; m < NTOK; m++) mx = fmaxf(mx, S[tid][m]);
            float sum = 0.f;
            for (int m = 0; m < NTOK; m++) { float e = __expf(S[tid][m] - mx); S[tid][m] = e; sum += e; }
            float inv = 1.0f / sum;
            for (int m = 0; m < NTOK; m++) S[tid][m] *= inv;
        }
        __syncthreads();
        for (int idx = tid; idx < NTOK*32; idx += 256) {   // P @ V
            int n = idx / 32, d = idx - n*32;
            float acc = 0.f;
            for (int m = 0; m < NTOK; m++) acc += S[n][m] * b2f(qkvs[m][192 + h*32 + d]);
            xnb[n][h*32 + d] = f2b(acc);
        }
        __syncthreads();
    }

    // ---- proj (96x96 weights fit in ws exactly) + residual + scatter-write ----
    for (int idx = tid; idx < 96*96; idx += 256) ws[idx] = f2b(projw[idx]);
    __syncthreads();
    for (int idx = tid; idx < NTOK*96; idx += 256) {
        int i = idx / NTOK, n = idx - i*NTOK;
        float acc = projb[i];
        for (int c = 0; c < 96; c++) acc += b2f(xnb[n][c]) * b2f(ws[i*96 + c]);
        int r = n/7, cc = n - r*7;
        int h = wh*7 + r + 3; if (h >= D_H) h -= D_H;
        int w = ww*7 + cc + 3; if (w >= D_W) w -= D_W;
        int off = ((b*96 + i)*D_H + h)*D_W + w;
        y[off] = x[off] + acc;
    }
}

// ---------------------------------------------------------------------------
// K2: MLP branch, in-place on d_out. 32 tokens per block (12544 blocks).
//   LN2 -> Linear(96->384) -> exact GELU -> Linear(384->96) -> residual.
// ---------------------------------------------------------------------------
__global__ __launch_bounds__(256) void k_mlp(
    float* __restrict__ y, const float* __restrict__ n2g, const float* __restrict__ n2b,
    const float* __restrict__ w1, const float* __restrict__ b1,
    const float* __restrict__ w2, const float* __restrict__ b2)
{
    __shared__ float t[96][32];          // normalized tokens (fp32)
    __shared__ bf16  wsb[96*96];         // weight chunk
    __shared__ bf16  h1[384*32];         // hidden activations
    __shared__ float mean_s[32], rstd_s[32];

    const int tid = threadIdx.x;
    const int T0 = blockIdx.x * 32;      // 50176 % 32 == 0 -> never straddles b
    const int b  = T0 / D_HW;
    const int p0 = T0 - b*D_HW;
    const int base = (b*96)*D_HW + p0;   // + c*D_HW + l

    for (int idx = tid; idx < 96*32; idx += 256) {
        int c = idx >> 5, l = idx & 31;
        t[c][l] = y[base + c*D_HW + l];
    }
    __syncthreads();
    if (tid < 32) {
        float s = 0.f, s2 = 0.f;
        for (int c = 0; c < 96; c++) { float v = t[c][tid]; s += v; s2 += v*v; }
        float m = s * (1.0f/96.0f);
        float var = s2 * (1.0f/96.0f) - m*m;
        mean_s[tid] = m;
        rstd_s[tid] = rsqrtf(var + 1e-5f);
    }
    __syncthreads();
    for (int idx = tid; idx < 96*32; idx += 256) {
        int c = idx >> 5, l = idx & 31;
        t[c][l] = (t[c][l] - mean_s[l]) * rstd_s[l] * n2g[c] + n2b[c];
    }

    // GEMM1 + exact GELU, 4 chunks of 96 hidden rows
    for (int jc = 0; jc < 4; jc++) {
        __syncthreads();
        for (int idx = tid; idx < 96*96; idx += 256) wsb[idx] = f2b(w1[jc*9216 + idx]);
        __syncthreads();
        for (int idx = tid; idx < 96*32; idx += 256) {
            int jj = idx >> 5, l = idx & 31;
            float acc = b1[jc*96 + jj];
            for (int c = 0; c < 96; c++) acc += t[c][l] * b2f(wsb[jj*96 + c]);
            float g = acc * 0.5f * (1.0f + erff(acc * 0.7071067811865475f));
            h1[(jc*96 + jj)*32 + l] = f2b(g);
        }
    }

    // GEMM2 (accumulate in registers across 4 chunks) + residual
    float acc[12];
    for (int k = 0; k < 12; k++) acc[k] = 0.f;
    for (int jc = 0; jc < 4; jc++) {
        __syncthreads();
        for (int idx = tid; idx < 96*96; idx += 256) {
            int i = idx / 96, jj = idx - i*96;
            wsb[idx] = f2b(w2[i*384 + jc*96 + jj]);
        }
        __syncthreads();
        for (int k = 0; k < 12; k++) {
            int idx = tid + k*256;
            int i = idx >> 5, l = idx & 31;
            float a = acc[k];
            for (int jj = 0; jj < 96; jj++)
                a += b2f(h1[(jc*96 + jj)*32 + l]) * b2f(wsb[i*96 + jj]);
            acc[k] = a;
        }
    }
    for (int k = 0; k < 12; k++) {
        int idx = tid + k*256;
        int i = idx >> 5, l = idx & 31;
        int off = base + i*D_HW + l;
        y[off] = y[off] + b2[i] + acc[k];
    }
}

extern "C" void kernel_launch(void* const* d_in, const int* in_sizes, int n_in,
                              void* d_out, int out_size, void* d_ws, size_t ws_size,
                              hipStream_t stream) {
    const float* x    = (const float*)d_in[0];
    const float* n1g  = (const float*)d_in[1];
    const float* n1b  = (const float*)d_in[2];
    const float* qkvw = (const float*)d_in[3];
    const float* qkvb = (const float*)d_in[4];
    const float* relt = (const float*)d_in[5];
    const float* projw= (const float*)d_in[6];
    const float* projb= (const float*)d_in[7];
    const float* n2g  = (const float*)d_in[8];
    const float* n2b  = (const float*)d_in[9];
    const float* w1   = (const float*)d_in[10];
    const float* b1   = (const float*)d_in[11];
    const float* w2   = (const float*)d_in[12];
    const float* b2   = (const float*)d_in[13];
    float* y = (float*)d_out;

    k_attn<<<8192, 256, 0, stream>>>(x, n1g, n1b, qkvw, qkvb, relt, projw, projb, y);
    k_mlp<<<12544, 256, 0, stream>>>(y, n2g, n2b, w1, b1, w2, b2);
}

// Round 3
// 1553.298 us; speedup vs baseline: 3.0158x; 3.0158x over previous
//
#include <hip/hip_runtime.h>
#include <hip/hip_bf16.h>

typedef __attribute__((ext_vector_type(8))) short short8;
typedef __attribute__((ext_vector_type(4))) float f32x4;

#define D_H   224
#define D_W   224
#define D_HW  50176
#define SCALE 0.17677669529663687f  // 32^-0.5

static __device__ __forceinline__ short f2s(float v) {
    union { __hip_bfloat16 b; short s; } u; u.b = __float2bfloat16(v); return u.s;
}
static __device__ __forceinline__ float s2f(short s) {
    union { short s; __hip_bfloat16 b; } u; u.s = s; return __bfloat162float(u.b);
}

#define MFMA(a, b, c) __builtin_amdgcn_mfma_f32_16x16x32_bf16((a), (b), (c), 0, 0, 0)

// ---------------------------------------------------------------------------
// K1: one block per window. MFMA everywhere.
//   LDS (61.8 KB, 2 blocks/CU):
//     qk [64][200]  Q(0..95, pre-scaled) K(96..191); PV output overwrites Q cols
//     vt [96][72]   V stored d-major (rows=channel, cols=token) for PV B-frags
//     region: xs[64][104] + wb[48][104]  (QKV/proj phases) ALIASED BY ps[64][72]
// ---------------------------------------------------------------------------
__global__ __launch_bounds__(256) void k_attn(
    const float* __restrict__ x, const float* __restrict__ n1g, const float* __restrict__ n1b,
    const float* __restrict__ qkvw, const float* __restrict__ qkvb, const float* __restrict__ relt,
    const float* __restrict__ projw, const float* __restrict__ projb, float* __restrict__ y)
{
    __shared__ short qk[64][200];                       // 25600 B
    __shared__ short vt[96][72];                        // 13824 B
    __shared__ __align__(16) char region[64*104*2 + 48*104*2];  // 23296 B
    short (*xs)[104] = (short(*)[104])region;
    short (*wb)[104] = (short(*)[104])(region + 64*104*2);
    short (*ps)[72]  = (short(*)[72])region;            // aliases xs (dead after QKV)
    __shared__ int   cnt_s[49];
    __shared__ float mean_s[49], rstd_s[49];

    const int tid  = threadIdx.x;
    const int wave = tid >> 6, lane = tid & 63;
    const int l16  = lane & 15, q8 = (lane >> 4) * 8, q4 = (lane >> 4) * 4;
    const int t0   = wave * 16;

    const int wi = blockIdx.x;
    const int b  = wi >> 10, nw = wi & 1023;
    const int wh = nw >> 5, ww = nw & 31;

    // ---- region labels + gather tokens (zero-pad rows 49..63) ----
    if (tid < 49) {
        int r = tid / 7, c = tid - r * 7;
        int sh = wh * 7 + r, sw = ww * 7 + c;
        int rh = (sh < 217) ? 0 : ((sh < 221) ? 1 : 2);
        int rw = (sw < 217) ? 0 : ((sw < 221) ? 1 : 2);
        cnt_s[tid] = rh * 3 + rw;
    }
    for (int idx = tid; idx < 64 * 96; idx += 256) {
        int c = idx >> 6, t = idx & 63;
        float v = 0.f;
        if (t < 49) {
            int r = t / 7, cc = t - r * 7;
            int h = wh * 7 + r + 3; if (h >= D_H) h -= D_H;
            int w = ww * 7 + cc + 3; if (w >= D_W) w -= D_W;
            v = x[((b * 96 + c) * D_H + h) * D_W + w];
        }
        xs[t][c] = f2s(v);
    }
    __syncthreads();

    // ---- LayerNorm1 ----
    if (tid < 49) {
        float s = 0.f, s2 = 0.f;
        for (int c = 0; c < 96; c++) { float v = s2f(xs[tid][c]); s += v; s2 += v * v; }
        float m = s * (1.f / 96.f);
        float var = s2 * (1.f / 96.f) - m * m;
        mean_s[tid] = m; rstd_s[tid] = rsqrtf(var + 1e-5f);
    }
    __syncthreads();
    for (int idx = tid; idx < 49 * 96; idx += 256) {
        int t = idx / 96, c = idx - t * 96;
        xs[t][c] = f2s((s2f(xs[t][c]) - mean_s[t]) * rstd_s[t] * n1g[c] + n1b[c]);
    }

    // ---- QKV: 6 chunks of 48 output channels ----
    for (int jc = 0; jc < 6; jc++) {
        __syncthreads();
        for (int idx = tid; idx < 48 * 96; idx += 256) {
            int j = idx / 96, c = idx - j * 96;
            wb[j][c] = f2s(qkvw[(jc * 48 + j) * 96 + c]);
        }
        __syncthreads();
        short8 a0 = *(const short8*)&xs[t0 + l16][q8];
        short8 a1 = *(const short8*)&xs[t0 + l16][32 + q8];
        short8 a2 = *(const short8*)&xs[t0 + l16][64 + q8];
        for (int nt = 0; nt < 3; nt++) {
            f32x4 acc = {0.f, 0.f, 0.f, 0.f};
            acc = MFMA(a0, *(const short8*)&wb[nt * 16 + l16][q8],      acc);
            acc = MFMA(a1, *(const short8*)&wb[nt * 16 + l16][32 + q8], acc);
            acc = MFMA(a2, *(const short8*)&wb[nt * 16 + l16][64 + q8], acc);
            int j = jc * 48 + nt * 16 + l16;
            float bias = qkvb[j];
#pragma unroll
            for (int r = 0; r < 4; r++) {
                int t = t0 + q4 + r;
                float v = acc[r] + bias;
                if (jc < 2)      qk[t][j] = f2s(v * SCALE);   // Q (pre-scaled)
                else if (jc < 4) qk[t][j] = f2s(v);           // K
                else             vt[j - 192][t] = f2s(v);     // V (d-major)
            }
        }
    }

    // ---- attention heads ----
    for (int h = 0; h < 3; h++) {
        __syncthreads();
        // S = Qs K^T + bias + mask (bf16, in ps)
        short8 aq = *(const short8*)&qk[t0 + l16][h * 32 + q8];
        for (int nt = 0; nt < 4; nt++) {
            f32x4 acc = {0.f, 0.f, 0.f, 0.f};
            short8 bk = *(const short8*)&qk[nt * 16 + l16][96 + h * 32 + q8];
            acc = MFMA(aq, bk, acc);
            int m  = nt * 16 + l16;
            int mm = (m < 49) ? m : 48;
            int r2 = mm / 7, c2 = mm - r2 * 7;
            int cm = cnt_s[mm];
#pragma unroll
            for (int r = 0; r < 4; r++) {
                int n  = t0 + q4 + r;
                int nn = (n < 49) ? n : 48;
                int r1 = nn / 7, c1 = nn - r1 * 7;
                int ridx = (r1 - r2 + 6) * 13 + (c1 - c2 + 6);
                float v = acc[r] + relt[ridx * 3 + h];
                if (cnt_s[nn] != cm) v -= 100.f;
                ps[n][m] = f2s(v);
            }
        }
        __syncthreads();
        // softmax over valid 49 cols; zero the padded cols
        if (tid < 49) {
            float mx = -1e30f;
            for (int m = 0; m < 49; m++) mx = fmaxf(mx, s2f(ps[tid][m]));
            float sum = 0.f;
            for (int m = 0; m < 49; m++) sum += __expf(s2f(ps[tid][m]) - mx);
            float inv = 1.f / sum;
            for (int m = 0; m < 49; m++) ps[tid][m] = f2s(__expf(s2f(ps[tid][m]) - mx) * inv);
            for (int m = 49; m < 64; m++) ps[tid][m] = 0;
        }
        __syncthreads();
        // PV -> overwrite dead Q columns of this head
        short8 p0 = *(const short8*)&ps[t0 + l16][q8];
        short8 p1 = *(const short8*)&ps[t0 + l16][32 + q8];
        for (int nt = 0; nt < 2; nt++) {
            f32x4 acc = {0.f, 0.f, 0.f, 0.f};
            acc = MFMA(p0, *(const short8*)&vt[h * 32 + nt * 16 + l16][q8],      acc);
            acc = MFMA(p1, *(const short8*)&vt[h * 32 + nt * 16 + l16][32 + q8], acc);
            int d = nt * 16 + l16;
#pragma unroll
            for (int r = 0; r < 4; r++) {
                int t = t0 + q4 + r;
                if (t < 49) qk[t][h * 32 + d] = f2s(acc[r]);
            }
        }
    }

    // ---- proj + residual, 2 chunks of 48 output channels ----
    for (int pc = 0; pc < 2; pc++) {
        __syncthreads();
        for (int idx = tid; idx < 48 * 96; idx += 256) {
            int j = idx / 96, c = idx - j * 96;
            wb[j][c] = f2s(projw[(pc * 48 + j) * 96 + c]);
        }
        __syncthreads();
        short8 o0 = *(const short8*)&qk[t0 + l16][q8];
        short8 o1 = *(const short8*)&qk[t0 + l16][32 + q8];
        short8 o2 = *(const short8*)&qk[t0 + l16][64 + q8];
        for (int nt = 0; nt < 3; nt++) {
            f32x4 acc = {0.f, 0.f, 0.f, 0.f};
            acc = MFMA(o0, *(const short8*)&wb[nt * 16 + l16][q8],      acc);
            acc = MFMA(o1, *(const short8*)&wb[nt * 16 + l16][32 + q8], acc);
            acc = MFMA(o2, *(const short8*)&wb[nt * 16 + l16][64 + q8], acc);
            int i = pc * 48 + nt * 16 + l16;
            float pb = projb[i];
#pragma unroll
            for (int r = 0; r < 4; r++) {
                int t = t0 + q4 + r;
                if (t < 49) {
                    int rr = t / 7, cc = t - rr * 7;
                    int hh = wh * 7 + rr + 3; if (hh >= D_H) hh -= D_H;
                    int w2 = ww * 7 + cc + 3; if (w2 >= D_W) w2 -= D_W;
                    int off = ((b * 96 + i) * D_H + hh) * D_W + w2;
                    y[off] = x[off] + acc[r] + pb;
                }
            }
        }
    }
}

// ---------------------------------------------------------------------------
// K2: MLP, 64 tokens/block (6272 blocks), MFMA, fused chunk pipeline.
//   LDS 47 KB -> 3 blocks/CU. In-place on y.
// ---------------------------------------------------------------------------
__global__ __launch_bounds__(256) void k_mlp(
    float* __restrict__ y, const float* __restrict__ n2g, const float* __restrict__ n2b,
    const float* __restrict__ w1, const float* __restrict__ b1,
    const float* __restrict__ w2, const float* __restrict__ b2)
{
    __shared__ short xs[64][104];    // normalized tokens; reused for epilogue
    __shared__ short wb[96][104];    // W1 or W2 chunk
    __shared__ short hb[64][104];    // GELU(H) chunk
    __shared__ float mean_s[64], rstd_s[64];

    const int tid  = threadIdx.x;
    const int wave = tid >> 6, lane = tid & 63;
    const int l16  = lane & 15, q8 = (lane >> 4) * 8, q4 = (lane >> 4) * 4;
    const int t0   = wave * 16;

    const int T0 = blockIdx.x * 64;            // 50176 % 64 == 0
    const int b  = T0 / D_HW;
    const int p0 = T0 - b * D_HW;
    const int base = (b * 96) * D_HW + p0;

    for (int idx = tid; idx < 64 * 96; idx += 256) {
        int c = idx >> 6, t = idx & 63;
        xs[t][c] = f2s(y[base + c * D_HW + t]);
    }
    __syncthreads();
    if (tid < 64) {
        float s = 0.f, s2 = 0.f;
        for (int c = 0; c < 96; c++) { float v = s2f(xs[tid][c]); s += v; s2 += v * v; }
        float m = s * (1.f / 96.f);
        float var = s2 * (1.f / 96.f) - m * m;
        mean_s[tid] = m; rstd_s[tid] = rsqrtf(var + 1e-5f);
    }
    __syncthreads();
    for (int idx = tid; idx < 64 * 96; idx += 256) {
        int c = idx >> 6, t = idx & 63;
        xs[t][c] = f2s((s2f(xs[t][c]) - mean_s[t]) * rstd_s[t] * n2g[c] + n2b[c]);
    }

    f32x4 c2[6];
#pragma unroll
    for (int nt = 0; nt < 6; nt++) c2[nt] = (f32x4){0.f, 0.f, 0.f, 0.f};

    for (int jc = 0; jc < 4; jc++) {
        // --- stage W1 chunk, compute H = gelu(Xn W1c^T + b1) ---
        __syncthreads();
        for (int idx = tid; idx < 96 * 96; idx += 256) {
            int j = idx / 96, c = idx - j * 96;
            wb[j][c] = f2s(w1[(jc * 96 + j) * 96 + c]);
        }
        __syncthreads();
        {
            short8 a0 = *(const short8*)&xs[t0 + l16][q8];
            short8 a1 = *(const short8*)&xs[t0 + l16][32 + q8];
            short8 a2 = *(const short8*)&xs[t0 + l16][64 + q8];
            for (int nt = 0; nt < 6; nt++) {
                f32x4 acc = {0.f, 0.f, 0.f, 0.f};
                acc = MFMA(a0, *(const short8*)&wb[nt * 16 + l16][q8],      acc);
                acc = MFMA(a1, *(const short8*)&wb[nt * 16 + l16][32 + q8], acc);
                acc = MFMA(a2, *(const short8*)&wb[nt * 16 + l16][64 + q8], acc);
                int j = jc * 96 + nt * 16 + l16;
                float bb = b1[j];
#pragma unroll
                for (int r = 0; r < 4; r++) {
                    float v = acc[r] + bb;
                    float g = 0.5f * v * (1.f + erff(v * 0.7071067811865475f));
                    hb[t0 + q4 + r][nt * 16 + l16] = f2s(g);
                }
            }
        }
        // --- stage W2 chunk, accumulate C2 += H W2c^T ---
        __syncthreads();
        for (int idx = tid; idx < 96 * 96; idx += 256) {
            int o = idx / 96, j = idx - o * 96;
            wb[o][j] = f2s(w2[o * 384 + jc * 96 + j]);
        }
        __syncthreads();
        {
            short8 a0 = *(const short8*)&hb[t0 + l16][q8];
            short8 a1 = *(const short8*)&hb[t0 + l16][32 + q8];
            short8 a2 = *(const short8*)&hb[t0 + l16][64 + q8];
            for (int nt = 0; nt < 6; nt++) {
                c2[nt] = MFMA(a0, *(const short8*)&wb[nt * 16 + l16][q8],      c2[nt]);
                c2[nt] = MFMA(a1, *(const short8*)&wb[nt * 16 + l16][32 + q8], c2[nt]);
                c2[nt] = MFMA(a2, *(const short8*)&wb[nt * 16 + l16][64 + q8], c2[nt]);
            }
        }
    }

    // --- epilogue through LDS for coalesced residual update ---
    for (int nt = 0; nt < 6; nt++) {
        int i = nt * 16 + l16;
        float bo = b2[i];
#pragma unroll
        for (int r = 0; r < 4; r++) xs[t0 + q4 + r][i] = f2s(bo + c2[nt][r]);
    }
    __syncthreads();
    for (int idx = tid; idx < 64 * 96; idx += 256) {
        int c = idx >> 6, t = idx & 63;
        int off = base + c * D_HW + t;
        y[off] = y[off] + s2f(xs[t][c]);
    }
}

extern "C" void kernel_launch(void* const* d_in, const int* in_sizes, int n_in,
                              void* d_out, int out_size, void* d_ws, size_t ws_size,
                              hipStream_t stream) {
    const float* x    = (const float*)d_in[0];
    const float* n1g  = (const float*)d_in[1];
    const float* n1b  = (const float*)d_in[2];
    const float* qkvw = (const float*)d_in[3];
    const float* qkvb = (const float*)d_in[4];
    const float* relt = (const float*)d_in[5];
    const float* projw= (const float*)d_in[6];
    const float* projb= (const float*)d_in[7];
    const float* n2g  = (const float*)d_in[8];
    const float* n2b  = (const float*)d_in[9];
    const float* w1   = (const float*)d_in[10];
    const float* b1   = (const float*)d_in[11];
    const float* w2   = (const float*)d_in[12];
    const float* b2   = (const float*)d_in[13];
    float* y = (float*)d_out;

    k_attn<<<8192, 256, 0, stream>>>(x, n1g, n1b, qkvw, qkvb, relt, projw, projb, y);
    k_mlp<<<6272, 256, 0, stream>>>(y, n2g, n2b, w1, b1, w2, b2);
}